// Round 2
// baseline (178.455 us; speedup 1.0000x reference)
//
#include <hip/hip_runtime.h>

// WeightedMSELoss: mean over [B,2] of |pred-label| * (1 + a - a*w[cell(pred)])
// Memory-bound full reduction: 134 MB read -> 1 float out.

constexpr int   GRIDN  = 201;
constexpr float ALPHA  = 0.1f;

__global__ __launch_bounds__(256) void wmse_reduce(
    const float4* __restrict__ pred4,
    const float4* __restrict__ lab4,
    const float*  __restrict__ wg,
    float*        __restrict__ out,
    int n4, float scale)
{
    float acc = 0.0f;
    const int stride = gridDim.x * blockDim.x;
    for (int i = blockIdx.x * blockDim.x + threadIdx.x; i < n4; i += stride) {
        const float4 p = pred4[i];
        const float4 l = lab4[i];

        // row 0: (lat, lon) = (p.x, p.y)
        {
            const float e   = fabsf(p.x - l.x) + fabsf(p.y - l.y);
            const float lat = p.x * 180.0f - 90.0f;
            const float lon = p.y * 360.0f - 180.0f;
            int xi = (int)floorf(lat / 0.9f) + 100;
            int yi = (int)floorf(lon / 1.8f) + 100;
            xi = min(max(xi, 0), GRIDN - 1);
            yi = min(max(yi, 0), GRIDN - 1);
            const float w = wg[xi * GRIDN + yi];
            acc += e * (1.0f + ALPHA - ALPHA * w);
        }
        // row 1: (lat, lon) = (p.z, p.w)
        {
            const float e   = fabsf(p.z - l.z) + fabsf(p.w - l.w);
            const float lat = p.z * 180.0f - 90.0f;
            const float lon = p.w * 360.0f - 180.0f;
            int xi = (int)floorf(lat / 0.9f) + 100;
            int yi = (int)floorf(lon / 1.8f) + 100;
            xi = min(max(xi, 0), GRIDN - 1);
            yi = min(max(yi, 0), GRIDN - 1);
            const float w = wg[xi * GRIDN + yi];
            acc += e * (1.0f + ALPHA - ALPHA * w);
        }
    }

    // 64-lane wave reduction
    #pragma unroll
    for (int off = 32; off > 0; off >>= 1)
        acc += __shfl_down(acc, off, 64);

    __shared__ float lds[4];
    const int lane = threadIdx.x & 63;
    const int wid  = threadIdx.x >> 6;
    if (lane == 0) lds[wid] = acc;
    __syncthreads();
    if (threadIdx.x == 0) {
        const float s = lds[0] + lds[1] + lds[2] + lds[3];
        atomicAdd(out, s * scale);
    }
}

extern "C" void kernel_launch(void* const* d_in, const int* in_sizes, int n_in,
                              void* d_out, int out_size, void* d_ws, size_t ws_size,
                              hipStream_t stream) {
    const float4* pred = (const float4*)d_in[0];
    const float4* lab  = (const float4*)d_in[1];
    const float*  wg   = (const float*)d_in[2];
    float*        out  = (float*)d_out;

    const long long total = (long long)in_sizes[0];   // B*2 floats
    const int   n4    = (int)(total / 4);             // float4 count per array
    const float scale = 1.0f / (float)total;

    // d_out is re-poisoned to 0xAA before every timed launch -> zero it here.
    hipMemsetAsync(d_out, 0, sizeof(float), stream);

    const int block = 256;
    const int grid  = 2048;   // 256 CU * 8 blocks; grid-stride covers the rest
    wmse_reduce<<<grid, block, 0, stream>>>(pred, lab, wg, out, n4, scale);
}

// Round 3
// 153.644 us; speedup vs baseline: 1.1615x; 1.1615x over previous
//
#include <hip/hip_runtime.h>

// WeightedMSELoss: mean over [B,2] of |pred-label| * (1 + a - a*w[cell(pred)])
// R2 redesign: the divergent weight-grid gather (161 KB table, misses the
// 32 KB L1 on nearly every lane) was the bottleneck (73 us, 11% HBM, 13%
// VALU, ~0 HBM traffic on warm replays). Stage the full table in LDS
// (161,604 B <= 160 KiB) -> gather becomes a ~10-cycle ds_read_b32.
// One 1024-thread block per CU (16 waves), grid = 256 CUs, 16 iters/thread.

constexpr int   GRIDN  = 201;
constexpr int   GRIDSZ = GRIDN * GRIDN;   // 40401
constexpr float ALPHA  = 0.1f;

__global__ __launch_bounds__(1024) void wmse_reduce(
    const float4* __restrict__ pred4,
    const float4* __restrict__ lab4,
    const float*  __restrict__ wg,
    float*        __restrict__ out,
    int n4, float scale)
{
    __shared__ float wg_lds[GRIDSZ];          // 161,604 B of 160 KiB

    // Stage weight grid: coalesced, 40 iterations per thread.
    for (int j = threadIdx.x; j < GRIDSZ; j += 1024)
        wg_lds[j] = wg[j];
    __syncthreads();

    float acc = 0.0f;
    const int stride = gridDim.x * blockDim.x;
    #pragma unroll 4
    for (int i = blockIdx.x * blockDim.x + threadIdx.x; i < n4; i += stride) {
        const float4 p = pred4[i];
        const float4 l = lab4[i];

        // row 0: (lat, lon) = (p.x, p.y)
        {
            const float e   = fabsf(p.x - l.x) + fabsf(p.y - l.y);
            const float lat = p.x * 180.0f - 90.0f;
            const float lon = p.y * 360.0f - 180.0f;
            int xi = (int)floorf(lat / 0.9f) + 100;
            int yi = (int)floorf(lon / 1.8f) + 100;
            xi = min(max(xi, 0), GRIDN - 1);
            yi = min(max(yi, 0), GRIDN - 1);
            const float w = wg_lds[xi * GRIDN + yi];
            acc += e * (1.0f + ALPHA - ALPHA * w);
        }
        // row 1: (lat, lon) = (p.z, p.w)
        {
            const float e   = fabsf(p.z - l.z) + fabsf(p.w - l.w);
            const float lat = p.z * 180.0f - 90.0f;
            const float lon = p.w * 360.0f - 180.0f;
            int xi = (int)floorf(lat / 0.9f) + 100;
            int yi = (int)floorf(lon / 1.8f) + 100;
            xi = min(max(xi, 0), GRIDN - 1);
            yi = min(max(yi, 0), GRIDN - 1);
            const float w = wg_lds[xi * GRIDN + yi];
            acc += e * (1.0f + ALPHA - ALPHA * w);
        }
    }

    // 64-lane wave reduction
    #pragma unroll
    for (int off = 32; off > 0; off >>= 1)
        acc += __shfl_down(acc, off, 64);

    __shared__ float red[16];
    const int lane = threadIdx.x & 63;
    const int wid  = threadIdx.x >> 6;
    if (lane == 0) red[wid] = acc;
    __syncthreads();
    if (threadIdx.x == 0) {
        float s = 0.0f;
        #pragma unroll
        for (int k = 0; k < 16; ++k) s += red[k];
        atomicAdd(out, s * scale);
    }
}

extern "C" void kernel_launch(void* const* d_in, const int* in_sizes, int n_in,
                              void* d_out, int out_size, void* d_ws, size_t ws_size,
                              hipStream_t stream) {
    const float4* pred = (const float4*)d_in[0];
    const float4* lab  = (const float4*)d_in[1];
    const float*  wg   = (const float*)d_in[2];
    float*        out  = (float*)d_out;

    const long long total = (long long)in_sizes[0];   // B*2 floats
    const int   n4    = (int)(total / 4);             // float4 count per array
    const float scale = 1.0f / (float)total;

    // d_out is re-poisoned to 0xAA before every timed launch -> zero it here.
    hipMemsetAsync(d_out, 0, sizeof(float), stream);

    const int block = 1024;   // 16 waves; LDS (161.6 KB) limits to 1 block/CU
    const int grid  = 256;    // one block per CU; 16 main-loop iters/thread
    wmse_reduce<<<grid, block, 0, stream>>>(pred, lab, wg, out, n4, scale);
}